// Round 3
// baseline (104350.476 us; speedup 1.0000x reference)
//
#include <hip/hip_runtime.h>
#include <hip/hip_cooperative_groups.h>

namespace cg = cooperative_groups;

typedef __attribute__((ext_vector_type(8))) short short8;
typedef __attribute__((ext_vector_type(4))) float f32x4;

__device__ __forceinline__ unsigned short f2bf(float f) {
  unsigned int u = __float_as_uint(f);
  u += 0x7FFFu + ((u >> 16) & 1u);
  return (unsigned short)(u >> 16);
}
__device__ __forceinline__ float bf2f(unsigned short h) {
  unsigned int u = ((unsigned int)h) << 16;
  return __uint_as_float(u);
}

// ------------- split pack fp32 -> (hi, lo) bf16, n % 4 == 0 -------------
__global__ __launch_bounds__(256) void pack_split_kernel(const float* __restrict__ src,
                                                         unsigned short* __restrict__ hi,
                                                         unsigned short* __restrict__ lo,
                                                         int n) {
  int i = (blockIdx.x * 256 + threadIdx.x) * 4;
  if (i >= n) return;
  float4 v = *(const float4*)(src + i);
  ushort4 h, l;
  h.x = f2bf(v.x); l.x = f2bf(v.x - bf2f(h.x));
  h.y = f2bf(v.y); l.y = f2bf(v.y - bf2f(h.y));
  h.z = f2bf(v.z); l.z = f2bf(v.z - bf2f(h.z));
  h.w = f2bf(v.w); l.w = f2bf(v.w - bf2f(h.w));
  *(ushort4*)(hi + i) = h;
  *(ushort4*)(lo + i) = l;
}

// ------- split pack + transpose: dst[n][k] = split_bf16(src[k][n]) -------
__global__ __launch_bounds__(256) void packT_split_kernel(const float* __restrict__ src,
                                                          unsigned short* __restrict__ hi,
                                                          unsigned short* __restrict__ lo,
                                                          int kbits, int N) {
  int idx = blockIdx.x * 256 + threadIdx.x;
  int K = 1 << kbits;
  int n = idx >> kbits;
  int k = idx & (K - 1);
  float v = src[k * N + n];
  unsigned short h = f2bf(v);
  hi[idx] = h;
  lo[idx] = f2bf(v - bf2f(h));
}

// ------------- plain pack + transpose: dst[n][k] = bf16(src[k][n]) -------------
__global__ __launch_bounds__(256) void packT_bf16_kernel(const float* __restrict__ src,
                                                         unsigned short* __restrict__ dst,
                                                         int kbits, int N) {
  int idx = blockIdx.x * 256 + threadIdx.x;
  int K = 1 << kbits;
  int n = idx >> kbits;
  int k = idx & (K - 1);
  dst[idx] = f2bf(src[k * N + n]);
}

// ------------- fp32 transpose 1024x1024: Wt[c][k] = W[k][c] -------------
__global__ __launch_bounds__(256) void transpose1024_kernel(const float* __restrict__ W,
                                                            float* __restrict__ Wt) {
  int idx = blockIdx.x * 256 + threadIdx.x;
  int c = idx >> 10, k = idx & 1023;
  Wt[idx] = W[k * 1024 + c];
}

// ------- split-precision MFMA GEMM: C = (Ahi+Alo) @ (Bhi+Blo)^T + bias -------
// 3-term: hi*hi + lo*hi + hi*lo. A: M x K, Bt: N x K. C fp32 M x N.
__global__ __launch_bounds__(256) void gemm_bf16x2_kernel(
    const unsigned short* __restrict__ Ahi, const unsigned short* __restrict__ Alo,
    const unsigned short* __restrict__ Bthi, const unsigned short* __restrict__ Btlo,
    const float* __restrict__ bias, float* __restrict__ C,
    int M, int N, int K) {
  __shared__ short Ah[64][40], Al[64][40], Bh[64][40], Bl[64][40];

  const int tid = threadIdx.x;
  const int wave = tid >> 6;
  const int lane = tid & 63;
  const int quad = lane >> 4;
  const int l16 = lane & 15;
  const int row0 = blockIdx.y * 64;
  const int col0 = blockIdx.x * 64;

  f32x4 acc[4];
  const f32x4 zero = {0.f, 0.f, 0.f, 0.f};
#pragma unroll
  for (int i = 0; i < 4; i++) acc[i] = zero;

  const int sr = tid >> 2;
  const int sseg = tid & 3;

  for (int k0 = 0; k0 < K; k0 += 32) {
    {
      long aoff = (long)(row0 + sr) * K + k0 + sseg * 8;
      long boff = (long)(col0 + sr) * K + k0 + sseg * 8;
      *(short8*)(&Ah[sr][sseg * 8]) = *(const short8*)(Ahi + aoff);
      *(short8*)(&Al[sr][sseg * 8]) = *(const short8*)(Alo + aoff);
      *(short8*)(&Bh[sr][sseg * 8]) = *(const short8*)(Bthi + boff);
      *(short8*)(&Bl[sr][sseg * 8]) = *(const short8*)(Btlo + boff);
    }
    __syncthreads();
    short8 ah = *(const short8*)(&Ah[wave * 16 + l16][quad * 8]);
    short8 al = *(const short8*)(&Al[wave * 16 + l16][quad * 8]);
#pragma unroll
    for (int nt = 0; nt < 4; nt++) {
      short8 bh = *(const short8*)(&Bh[nt * 16 + l16][quad * 8]);
      short8 bl = *(const short8*)(&Bl[nt * 16 + l16][quad * 8]);
      acc[nt] = __builtin_amdgcn_mfma_f32_16x16x32_bf16(al, bh, acc[nt], 0, 0, 0);
      acc[nt] = __builtin_amdgcn_mfma_f32_16x16x32_bf16(ah, bl, acc[nt], 0, 0, 0);
      acc[nt] = __builtin_amdgcn_mfma_f32_16x16x32_bf16(ah, bh, acc[nt], 0, 0, 0);
    }
    __syncthreads();
  }

#pragma unroll
  for (int nt = 0; nt < 4; nt++) {
    int col = col0 + nt * 16 + l16;
    float bv = bias[col];
#pragma unroll
    for (int r = 0; r < 4; r++) {
      int row = row0 + wave * 16 + quad * 4 + r;
      C[(long)row * N + col] = acc[nt][r] + bv;
    }
  }
}

// ---------------- plain bf16 MFMA GEMM (for the output projection) ----------------
__global__ __launch_bounds__(256) void gemm_bf16_kernel(
    const unsigned short* __restrict__ A,
    const unsigned short* __restrict__ Bt,
    const float* __restrict__ bias,
    float* __restrict__ C,
    int M, int N, int K, int relu) {
  __shared__ short As[64][40];
  __shared__ short Bs[64][40];

  const int tid = threadIdx.x;
  const int wave = tid >> 6;
  const int lane = tid & 63;
  const int quad = lane >> 4;
  const int l16 = lane & 15;
  const int row0 = blockIdx.y * 64;
  const int col0 = blockIdx.x * 64;

  f32x4 acc[4];
  const f32x4 zero = {0.f, 0.f, 0.f, 0.f};
#pragma unroll
  for (int i = 0; i < 4; i++) acc[i] = zero;

  const int sr = tid >> 2;
  const int sseg = tid & 3;

  for (int k0 = 0; k0 < K; k0 += 32) {
    {
      short8 va = *(const short8*)(A + (long)(row0 + sr) * K + k0 + sseg * 8);
      *(short8*)(&As[sr][sseg * 8]) = va;
      short8 vb = *(const short8*)(Bt + (long)(col0 + sr) * K + k0 + sseg * 8);
      *(short8*)(&Bs[sr][sseg * 8]) = vb;
    }
    __syncthreads();
    short8 a = *(const short8*)(&As[wave * 16 + l16][quad * 8]);
#pragma unroll
    for (int nt = 0; nt < 4; nt++) {
      short8 b = *(const short8*)(&Bs[nt * 16 + l16][quad * 8]);
      acc[nt] = __builtin_amdgcn_mfma_f32_16x16x32_bf16(a, b, acc[nt], 0, 0, 0);
    }
    __syncthreads();
  }

#pragma unroll
  for (int nt = 0; nt < 4; nt++) {
    int col = col0 + nt * 16 + l16;
    float bv = bias[col];
#pragma unroll
    for (int r = 0; r < 4; r++) {
      int row = row0 + wave * 16 + quad * 4 + r;
      float v = acc[nt][r] + bv;
      if (relu) v = fmaxf(v, 0.f);
      C[(long)row * N + col] = v;
    }
  }
}

// ---------------- cooperative recurrence (fp32, exact) ----------------
__global__ __launch_bounds__(256) void recurrence_kernel(
    const float* __restrict__ xz, const float* __restrict__ xr, const float* __restrict__ xs,
    const float* __restrict__ Wzt, const float* __restrict__ Wrt, const float* __restrict__ Wst,
    float* __restrict__ h, float* __restrict__ rh,
    unsigned short* __restrict__ hs_bf, float* __restrict__ hfin) {
  extern __shared__ float sm[];  // 16 rows * 1032 floats
  cg::grid_group grid = cg::this_grid();

  const int tid = threadIdx.x;
  const int bh = tid >> 4;
  const int cc = tid & 15;
  const int g = blockIdx.x >> 6;
  const int c = blockIdx.x & 63;
  const int b = g * 16 + bh;
  const int col = c * 16 + cc;

  h[b * 1024 + col] = 0.f;
  __threadfence();
  grid.sync();

  const float4* wz4 = (const float4*)(Wzt + (long)col * 1024);
  const float4* wr4 = (const float4*)(Wrt + (long)col * 1024);
  const float4* ws4 = (const float4*)(Wst + (long)col * 1024);
  const float4* h4 = (const float4*)(sm + bh * 1032);

  for (int t = 0; t < 512; t++) {
    for (int i = tid; i < 16 * 1024; i += 256) {
      int bb = i >> 10, k = i & 1023;
      sm[bb * 1032 + k] = h[(g * 16 + bb) * 1024 + k];
    }
    __syncthreads();

    float dz0 = 0.f, dz1 = 0.f, dr0 = 0.f, dr1 = 0.f;
#pragma unroll 4
    for (int kc = 0; kc < 256; kc += 2) {
      float4 hv0 = h4[kc];
      float4 az0 = wz4[kc];
      float4 ag0 = wr4[kc];
      dz0 = fmaf(hv0.x, az0.x, dz0); dz0 = fmaf(hv0.y, az0.y, dz0);
      dz0 = fmaf(hv0.z, az0.z, dz0); dz0 = fmaf(hv0.w, az0.w, dz0);
      dr0 = fmaf(hv0.x, ag0.x, dr0); dr0 = fmaf(hv0.y, ag0.y, dr0);
      dr0 = fmaf(hv0.z, ag0.z, dr0); dr0 = fmaf(hv0.w, ag0.w, dr0);
      float4 hv1 = h4[kc + 1];
      float4 az1 = wz4[kc + 1];
      float4 ag1 = wr4[kc + 1];
      dz1 = fmaf(hv1.x, az1.x, dz1); dz1 = fmaf(hv1.y, az1.y, dz1);
      dz1 = fmaf(hv1.z, az1.z, dz1); dz1 = fmaf(hv1.w, az1.w, dz1);
      dr1 = fmaf(hv1.x, ag1.x, dr1); dr1 = fmaf(hv1.y, ag1.y, dr1);
      dr1 = fmaf(hv1.z, ag1.z, dr1); dr1 = fmaf(hv1.w, ag1.w, dr1);
    }

    const long xoff = ((long)b * 512 + t) * 1024 + col;
    float zt = 1.f / (1.f + expf(-(dz0 + dz1 + xz[xoff])));
    float rt = 1.f / (1.f + expf(-(dr0 + dr1 + xr[xoff])));
    float hold = sm[bh * 1032 + col];
    rh[b * 1024 + col] = rt * hold;
    __threadfence();
    grid.sync();

    for (int i = tid; i < 16 * 1024; i += 256) {
      int bb = i >> 10, k = i & 1023;
      sm[bb * 1032 + k] = rh[(g * 16 + bb) * 1024 + k];
    }
    __syncthreads();

    float ds0 = 0.f, ds1 = 0.f;
#pragma unroll 4
    for (int kc = 0; kc < 256; kc += 2) {
      float4 hv0 = h4[kc];
      float4 as0 = ws4[kc];
      ds0 = fmaf(hv0.x, as0.x, ds0); ds0 = fmaf(hv0.y, as0.y, ds0);
      ds0 = fmaf(hv0.z, as0.z, ds0); ds0 = fmaf(hv0.w, as0.w, ds0);
      float4 hv1 = h4[kc + 1];
      float4 as1 = ws4[kc + 1];
      ds1 = fmaf(hv1.x, as1.x, ds1); ds1 = fmaf(hv1.y, as1.y, ds1);
      ds1 = fmaf(hv1.z, as1.z, ds1); ds1 = fmaf(hv1.w, as1.w, ds1);
    }

    float st = tanhf(ds0 + ds1 + xs[xoff]);
    float hn = (1.f - zt) * hold + zt * st;
    h[b * 1024 + col] = hn;
    hs_bf[xoff] = f2bf(hn);
    if (t == 511) hfin[b * 1024 + col] = hn;
    __threadfence();
    grid.sync();
  }
}

// ---------------- launch ----------------
extern "C" void kernel_launch(void* const* d_in, const int* in_sizes, int n_in,
                              void* d_out, int out_size, void* d_ws, size_t ws_size,
                              hipStream_t stream) {
  const float* inputs = (const float*)d_in[0];
  const float* Wz = (const float*)d_in[1];
  const float* bz = (const float*)d_in[2];
  const float* Wr = (const float*)d_in[3];
  const float* br = (const float*)d_in[4];
  const float* Ws = (const float*)d_in[5];
  const float* bs = (const float*)d_in[6];
  const float* Wo = (const float*)d_in[7];
  const float* bo = (const float*)d_in[8];

  // Workspace layout (top = 491257856 B ~ 468.5 MiB; R1 proved >= 497.5 MiB works).
  // NOTE: hs_bf ALIASES Xhi+Xlo — X split buffers are dead after the x-proj
  // GEMMs; hs_bf is only written by the (later) recurrence kernel.
  char* w = (char*)d_ws;
  float* xz = (float*)(w + 0ll);                                    // 128 MB
  float* xr = (float*)(w + 134217728ll);                            // 128 MB
  float* xs = (float*)(w + 268435456ll);                            // 128 MB
  unsigned short* Xhi = (unsigned short*)(w + 402653184ll);         // 32 MB
  unsigned short* Xlo = (unsigned short*)(w + 436207616ll);         // 32 MB
  unsigned short* hs_bf = (unsigned short*)(w + 402653184ll);       // 64 MB (alias)
  unsigned short* WzxThi = (unsigned short*)(w + 469762048ll);      // 1 MB each
  unsigned short* WzxTlo = (unsigned short*)(w + 470810624ll);
  unsigned short* WrxThi = (unsigned short*)(w + 471859200ll);
  unsigned short* WrxTlo = (unsigned short*)(w + 472907776ll);
  unsigned short* WsxThi = (unsigned short*)(w + 473956352ll);
  unsigned short* WsxTlo = (unsigned short*)(w + 475004928ll);
  unsigned short* WoT = (unsigned short*)(w + 476053504ll);         // 2 MB
  float* Wzt = (float*)(w + 478150656ll);                           // 4 MB each
  float* Wrt = (float*)(w + 482344960ll);
  float* Wst = (float*)(w + 486539264ll);
  float* hbuf = (float*)(w + 490733568ll);                          // 256 KB
  float* rhbuf = (float*)(w + 490995712ll);                         // 256 KB -> ends 491257856

  float* out = (float*)d_out;
  float* hfin = out + 33554432;  // 64*512*1024

  // inputs -> split bf16
  hipLaunchKernelGGL(pack_split_kernel, dim3(16384), dim3(256), 0, stream,
                     inputs, Xhi, Xlo, 16777216);
  // input-projection weights (rows 1024..1535), transposed split bf16, K=512
  hipLaunchKernelGGL(packT_split_kernel, dim3(2048), dim3(256), 0, stream,
                     Wz + 1048576, WzxThi, WzxTlo, 9, 1024);
  hipLaunchKernelGGL(packT_split_kernel, dim3(2048), dim3(256), 0, stream,
                     Wr + 1048576, WrxThi, WrxTlo, 9, 1024);
  hipLaunchKernelGGL(packT_split_kernel, dim3(2048), dim3(256), 0, stream,
                     Ws + 1048576, WsxThi, WsxTlo, 9, 1024);
  // output weights transposed bf16, K=1024
  hipLaunchKernelGGL(packT_bf16_kernel, dim3(4096), dim3(256), 0, stream, Wo, WoT, 10, 1024);
  // recurrent weights fp32 transposed [col][k]
  hipLaunchKernelGGL(transpose1024_kernel, dim3(4096), dim3(256), 0, stream, Wz, Wzt);
  hipLaunchKernelGGL(transpose1024_kernel, dim3(4096), dim3(256), 0, stream, Wr, Wrt);
  hipLaunchKernelGGL(transpose1024_kernel, dim3(4096), dim3(256), 0, stream, Ws, Wst);

  // x-projections in split precision (near-fp32): xz/xr/xs = X @ Wx + b
  hipLaunchKernelGGL(gemm_bf16x2_kernel, dim3(16, 512), dim3(256), 0, stream,
                     Xhi, Xlo, WzxThi, WzxTlo, bz, xz, 32768, 1024, 512);
  hipLaunchKernelGGL(gemm_bf16x2_kernel, dim3(16, 512), dim3(256), 0, stream,
                     Xhi, Xlo, WrxThi, WrxTlo, br, xr, 32768, 1024, 512);
  hipLaunchKernelGGL(gemm_bf16x2_kernel, dim3(16, 512), dim3(256), 0, stream,
                     Xhi, Xlo, WsxThi, WsxTlo, bs, xs, 32768, 1024, 512);

  // sequential recurrence (cooperative, exact fp32, 2 grid syncs per step)
  // (X split buffers are dead from here on; hs_bf reuses their space.)
  void* args[] = {&xz, &xr, &xs, &Wzt, &Wrt, &Wst, &hbuf, &rhbuf, &hs_bf, &hfin};
  hipLaunchCooperativeKernel((const void*)recurrence_kernel, dim3(256), dim3(256),
                             args, 66048, stream);

  // outputs = relu(hs @ Wo + bo)
  hipLaunchKernelGGL(gemm_bf16_kernel, dim3(16, 512), dim3(256), 0, stream,
                     hs_bf, WoT, bo, out, 32768, 1024, 1024, 1);
}

// Round 4
// 44152.237 us; speedup vs baseline: 2.3634x; 2.3634x over previous
//
#include <hip/hip_runtime.h>
#include <hip/hip_cooperative_groups.h>

namespace cg = cooperative_groups;

typedef __attribute__((ext_vector_type(8))) short short8;
typedef __attribute__((ext_vector_type(4))) float f32x4;

__device__ __forceinline__ unsigned short f2bf(float f) {
  unsigned int u = __float_as_uint(f);
  u += 0x7FFFu + ((u >> 16) & 1u);
  return (unsigned short)(u >> 16);
}
__device__ __forceinline__ float bf2f(unsigned short h) {
  unsigned int u = ((unsigned int)h) << 16;
  return __uint_as_float(u);
}

// ------------- split pack fp32 -> (hi, lo) bf16, n % 4 == 0 -------------
__global__ __launch_bounds__(256) void pack_split_kernel(const float* __restrict__ src,
                                                         unsigned short* __restrict__ hi,
                                                         unsigned short* __restrict__ lo,
                                                         int n) {
  int i = (blockIdx.x * 256 + threadIdx.x) * 4;
  if (i >= n) return;
  float4 v = *(const float4*)(src + i);
  ushort4 h, l;
  h.x = f2bf(v.x); l.x = f2bf(v.x - bf2f(h.x));
  h.y = f2bf(v.y); l.y = f2bf(v.y - bf2f(h.y));
  h.z = f2bf(v.z); l.z = f2bf(v.z - bf2f(h.z));
  h.w = f2bf(v.w); l.w = f2bf(v.w - bf2f(h.w));
  *(ushort4*)(hi + i) = h;
  *(ushort4*)(lo + i) = l;
}

// ------- split pack + transpose: dst[n][k] = split_bf16(src[k][n]) -------
__global__ __launch_bounds__(256) void packT_split_kernel(const float* __restrict__ src,
                                                          unsigned short* __restrict__ hi,
                                                          unsigned short* __restrict__ lo,
                                                          int kbits, int N) {
  int idx = blockIdx.x * 256 + threadIdx.x;
  int K = 1 << kbits;
  int n = idx >> kbits;
  int k = idx & (K - 1);
  float v = src[k * N + n];
  unsigned short h = f2bf(v);
  hi[idx] = h;
  lo[idx] = f2bf(v - bf2f(h));
}

// ------------- plain pack + transpose: dst[n][k] = bf16(src[k][n]) -------------
__global__ __launch_bounds__(256) void packT_bf16_kernel(const float* __restrict__ src,
                                                         unsigned short* __restrict__ dst,
                                                         int kbits, int N) {
  int idx = blockIdx.x * 256 + threadIdx.x;
  int K = 1 << kbits;
  int n = idx >> kbits;
  int k = idx & (K - 1);
  dst[idx] = f2bf(src[k * N + n]);
}

// ------------- fp32 transpose 1024x1024: Wt[c][k] = W[k][c] -------------
__global__ __launch_bounds__(256) void transpose1024_kernel(const float* __restrict__ W,
                                                            float* __restrict__ Wt) {
  int idx = blockIdx.x * 256 + threadIdx.x;
  int c = idx >> 10, k = idx & 1023;
  Wt[idx] = W[k * 1024 + c];
}

// ------- split-precision MFMA GEMM: C = (Ahi+Alo) @ (Bhi+Blo)^T + bias -------
__global__ __launch_bounds__(256) void gemm_bf16x2_kernel(
    const unsigned short* __restrict__ Ahi, const unsigned short* __restrict__ Alo,
    const unsigned short* __restrict__ Bthi, const unsigned short* __restrict__ Btlo,
    const float* __restrict__ bias, float* __restrict__ C,
    int M, int N, int K) {
  __shared__ short Ah[64][40], Al[64][40], Bh[64][40], Bl[64][40];

  const int tid = threadIdx.x;
  const int wave = tid >> 6;
  const int lane = tid & 63;
  const int quad = lane >> 4;
  const int l16 = lane & 15;
  const int row0 = blockIdx.y * 64;
  const int col0 = blockIdx.x * 64;

  f32x4 acc[4];
  const f32x4 zero = {0.f, 0.f, 0.f, 0.f};
#pragma unroll
  for (int i = 0; i < 4; i++) acc[i] = zero;

  const int sr = tid >> 2;
  const int sseg = tid & 3;

  for (int k0 = 0; k0 < K; k0 += 32) {
    {
      long aoff = (long)(row0 + sr) * K + k0 + sseg * 8;
      long boff = (long)(col0 + sr) * K + k0 + sseg * 8;
      *(short8*)(&Ah[sr][sseg * 8]) = *(const short8*)(Ahi + aoff);
      *(short8*)(&Al[sr][sseg * 8]) = *(const short8*)(Alo + aoff);
      *(short8*)(&Bh[sr][sseg * 8]) = *(const short8*)(Bthi + boff);
      *(short8*)(&Bl[sr][sseg * 8]) = *(const short8*)(Btlo + boff);
    }
    __syncthreads();
    short8 ah = *(const short8*)(&Ah[wave * 16 + l16][quad * 8]);
    short8 al = *(const short8*)(&Al[wave * 16 + l16][quad * 8]);
#pragma unroll
    for (int nt = 0; nt < 4; nt++) {
      short8 bh = *(const short8*)(&Bh[nt * 16 + l16][quad * 8]);
      short8 bl = *(const short8*)(&Bl[nt * 16 + l16][quad * 8]);
      acc[nt] = __builtin_amdgcn_mfma_f32_16x16x32_bf16(al, bh, acc[nt], 0, 0, 0);
      acc[nt] = __builtin_amdgcn_mfma_f32_16x16x32_bf16(ah, bl, acc[nt], 0, 0, 0);
      acc[nt] = __builtin_amdgcn_mfma_f32_16x16x32_bf16(ah, bh, acc[nt], 0, 0, 0);
    }
    __syncthreads();
  }

#pragma unroll
  for (int nt = 0; nt < 4; nt++) {
    int col = col0 + nt * 16 + l16;
    float bv = bias[col];
#pragma unroll
    for (int r = 0; r < 4; r++) {
      int row = row0 + wave * 16 + quad * 4 + r;
      C[(long)row * N + col] = acc[nt][r] + bv;
    }
  }
}

// ---------------- plain bf16 MFMA GEMM (output projection) ----------------
__global__ __launch_bounds__(256) void gemm_bf16_kernel(
    const unsigned short* __restrict__ A,
    const unsigned short* __restrict__ Bt,
    const float* __restrict__ bias,
    float* __restrict__ C,
    int M, int N, int K, int relu) {
  __shared__ short As[64][40];
  __shared__ short Bs[64][40];

  const int tid = threadIdx.x;
  const int wave = tid >> 6;
  const int lane = tid & 63;
  const int quad = lane >> 4;
  const int l16 = lane & 15;
  const int row0 = blockIdx.y * 64;
  const int col0 = blockIdx.x * 64;

  f32x4 acc[4];
  const f32x4 zero = {0.f, 0.f, 0.f, 0.f};
#pragma unroll
  for (int i = 0; i < 4; i++) acc[i] = zero;

  const int sr = tid >> 2;
  const int sseg = tid & 3;

  for (int k0 = 0; k0 < K; k0 += 32) {
    {
      short8 va = *(const short8*)(A + (long)(row0 + sr) * K + k0 + sseg * 8);
      *(short8*)(&As[sr][sseg * 8]) = va;
      short8 vb = *(const short8*)(Bt + (long)(col0 + sr) * K + k0 + sseg * 8);
      *(short8*)(&Bs[sr][sseg * 8]) = vb;
    }
    __syncthreads();
    short8 a = *(const short8*)(&As[wave * 16 + l16][quad * 8]);
#pragma unroll
    for (int nt = 0; nt < 4; nt++) {
      short8 b = *(const short8*)(&Bs[nt * 16 + l16][quad * 8]);
      acc[nt] = __builtin_amdgcn_mfma_f32_16x16x32_bf16(a, b, acc[nt], 0, 0, 0);
    }
    __syncthreads();
  }

#pragma unroll
  for (int nt = 0; nt < 4; nt++) {
    int col = col0 + nt * 16 + l16;
    float bv = bias[col];
#pragma unroll
    for (int r = 0; r < 4; r++) {
      int row = row0 + wave * 16 + quad * 4 + r;
      float v = acc[nt][r] + bv;
      if (relu) v = fmaxf(v, 0.f);
      C[(long)row * N + col] = v;
    }
  }
}

// ---------------- MFMA cooperative recurrence ----------------
// 128 blocks x 256 threads. Blocks 0..63: z+r gates for cols [64b..64b+15]
// (Wz,Wr split-bf16 in LDS, 132KB). Blocks 64..127: s gate + h update.
// Weights staged into LDS ONCE; h / (r*h) cross steps as split-bf16 in global.
__global__ __launch_bounds__(256) void recurrence_mfma_kernel(
    const float* __restrict__ xz, const float* __restrict__ xr, const float* __restrict__ xs,
    const float* __restrict__ Wzt, const float* __restrict__ Wrt, const float* __restrict__ Wst,
    float* __restrict__ hbuf, float* __restrict__ zbuf,
    unsigned short* __restrict__ h_hi, unsigned short* __restrict__ h_lo,
    unsigned short* __restrict__ rh_hi, unsigned short* __restrict__ rh_lo,
    unsigned short* __restrict__ hs_bf, float* __restrict__ hfin) {
  extern __shared__ short smem[];  // [16][1032] x4 (zr-blocks) or x2 (s-blocks)
  cg::grid_group grid = cg::this_grid();

  const int tid = threadIdx.x;
  const int wave = tid >> 6;
  const int lane = tid & 63;
  const int quad = lane >> 4;
  const int l16 = lane & 15;
  const int bid = blockIdx.x;
  const bool is_s = (bid >= 64);
  const int c0 = (bid & 63) * 16;

  short* wh0 = smem;            // z (or s) hi
  short* wl0 = smem + 16512;    // z (or s) lo
  short* wh1 = smem + 33024;    // r hi
  short* wl1 = smem + 49536;    // r lo

  if (!is_s) {
    for (int i = tid; i < 16384; i += 256) {
      int n = i >> 10, k = i & 1023;
      float vz = Wzt[(c0 + n) * 1024 + k];
      unsigned short hz = f2bf(vz);
      wh0[n * 1032 + k] = (short)hz;
      wl0[n * 1032 + k] = (short)f2bf(vz - bf2f(hz));
      float vr = Wrt[(c0 + n) * 1024 + k];
      unsigned short hr = f2bf(vr);
      wh1[n * 1032 + k] = (short)hr;
      wl1[n * 1032 + k] = (short)f2bf(vr - bf2f(hr));
    }
  } else {
    for (int i = tid; i < 16384; i += 256) {
      int n = i >> 10, k = i & 1023;
      float vs = Wst[(c0 + n) * 1024 + k];
      unsigned short hs = f2bf(vs);
      wh0[n * 1032 + k] = (short)hs;
      wl0[n * 1032 + k] = (short)f2bf(vs - bf2f(hs));
    }
    // zero-init h for this block's columns (ws is poisoned)
    for (int i = tid; i < 1024; i += 256) {
      int row = i >> 4, col = c0 + (i & 15);
      hbuf[row * 1024 + col] = 0.f;
      h_hi[row * 1024 + col] = 0;
      h_lo[row * 1024 + col] = 0;
    }
  }
  __threadfence();
  grid.sync();

  const int aoff = (wave * 16 + l16) * 1024 + quad * 8;  // A-frag: row=lane&15 (+wave*16), k=quad*8+j
  const int boff = l16 * 1032 + quad * 8;                // B-frag from LDS [n][k]
  const int crow = wave * 16 + quad * 4;                 // C rows crow..crow+3
  const int col = c0 + l16;                              // C col

  for (int t = 0; t < 512; t++) {
    // ---- phase 1: z and r (blocks 0..63) ----
    if (!is_s) {
      f32x4 accz = {0.f, 0.f, 0.f, 0.f};
      f32x4 accr = {0.f, 0.f, 0.f, 0.f};
#pragma unroll 4
      for (int k0 = 0; k0 < 1024; k0 += 32) {
        short8 ah = *(const short8*)(h_hi + aoff + k0);
        short8 al = *(const short8*)(h_lo + aoff + k0);
        short8 bzh = *(const short8*)(wh0 + boff + k0);
        short8 bzl = *(const short8*)(wl0 + boff + k0);
        short8 brh = *(const short8*)(wh1 + boff + k0);
        short8 brl = *(const short8*)(wl1 + boff + k0);
        accz = __builtin_amdgcn_mfma_f32_16x16x32_bf16(al, bzh, accz, 0, 0, 0);
        accz = __builtin_amdgcn_mfma_f32_16x16x32_bf16(ah, bzl, accz, 0, 0, 0);
        accz = __builtin_amdgcn_mfma_f32_16x16x32_bf16(ah, bzh, accz, 0, 0, 0);
        accr = __builtin_amdgcn_mfma_f32_16x16x32_bf16(al, brh, accr, 0, 0, 0);
        accr = __builtin_amdgcn_mfma_f32_16x16x32_bf16(ah, brl, accr, 0, 0, 0);
        accr = __builtin_amdgcn_mfma_f32_16x16x32_bf16(ah, brh, accr, 0, 0, 0);
      }
#pragma unroll
      for (int rr = 0; rr < 4; rr++) {
        int rowg = crow + rr;
        long xoff = ((long)rowg * 512 + t) * 1024 + col;
        float zv = 1.f / (1.f + __expf(-(accz[rr] + xz[xoff])));
        zbuf[rowg * 1024 + col] = zv;
        float rv = 1.f / (1.f + __expf(-(accr[rr] + xr[xoff])));
        float rh = rv * hbuf[rowg * 1024 + col];
        unsigned short hi = f2bf(rh);
        rh_hi[rowg * 1024 + col] = hi;
        rh_lo[rowg * 1024 + col] = f2bf(rh - bf2f(hi));
      }
    }
    __threadfence();
    grid.sync();

    // ---- phase 2: s gate + h update (blocks 64..127) ----
    if (is_s) {
      f32x4 accs = {0.f, 0.f, 0.f, 0.f};
#pragma unroll 4
      for (int k0 = 0; k0 < 1024; k0 += 32) {
        short8 ah = *(const short8*)(rh_hi + aoff + k0);
        short8 al = *(const short8*)(rh_lo + aoff + k0);
        short8 bh = *(const short8*)(wh0 + boff + k0);
        short8 bl = *(const short8*)(wl0 + boff + k0);
        accs = __builtin_amdgcn_mfma_f32_16x16x32_bf16(al, bh, accs, 0, 0, 0);
        accs = __builtin_amdgcn_mfma_f32_16x16x32_bf16(ah, bl, accs, 0, 0, 0);
        accs = __builtin_amdgcn_mfma_f32_16x16x32_bf16(ah, bh, accs, 0, 0, 0);
      }
#pragma unroll
      for (int rr = 0; rr < 4; rr++) {
        int rowg = crow + rr;
        long xoff = ((long)rowg * 512 + t) * 1024 + col;
        float st = tanhf(accs[rr] + xs[xoff]);
        float zv = zbuf[rowg * 1024 + col];
        float hold = hbuf[rowg * 1024 + col];
        float hn = (1.f - zv) * hold + zv * st;
        hbuf[rowg * 1024 + col] = hn;
        unsigned short hi = f2bf(hn);
        h_hi[rowg * 1024 + col] = hi;
        h_lo[rowg * 1024 + col] = f2bf(hn - bf2f(hi));
        hs_bf[xoff] = f2bf(hn);
        if (t == 511) hfin[rowg * 1024 + col] = hn;
      }
    }
    __threadfence();
    grid.sync();
  }
}

// ---------------- launch ----------------
extern "C" void kernel_launch(void* const* d_in, const int* in_sizes, int n_in,
                              void* d_out, int out_size, void* d_ws, size_t ws_size,
                              hipStream_t stream) {
  const float* inputs = (const float*)d_in[0];
  const float* Wz = (const float*)d_in[1];
  const float* bz = (const float*)d_in[2];
  const float* Wr = (const float*)d_in[3];
  const float* br = (const float*)d_in[4];
  const float* Ws = (const float*)d_in[5];
  const float* bs = (const float*)d_in[6];
  const float* Wo = (const float*)d_in[7];
  const float* bo = (const float*)d_in[8];

  // Workspace layout, top = 491782144 B (~469 MiB; R1 proved >= 497.5 MiB exists).
  // hs_bf ALIASES Xhi/Xlo (dead after x-proj GEMMs).
  char* w = (char*)d_ws;
  float* xz = (float*)(w + 0ll);
  float* xr = (float*)(w + 134217728ll);
  float* xs = (float*)(w + 268435456ll);
  unsigned short* Xhi = (unsigned short*)(w + 402653184ll);
  unsigned short* Xlo = (unsigned short*)(w + 436207616ll);
  unsigned short* hs_bf = (unsigned short*)(w + 402653184ll);  // alias
  unsigned short* WzxThi = (unsigned short*)(w + 469762048ll);
  unsigned short* WzxTlo = (unsigned short*)(w + 470810624ll);
  unsigned short* WrxThi = (unsigned short*)(w + 471859200ll);
  unsigned short* WrxTlo = (unsigned short*)(w + 472907776ll);
  unsigned short* WsxThi = (unsigned short*)(w + 473956352ll);
  unsigned short* WsxTlo = (unsigned short*)(w + 475004928ll);
  unsigned short* WoT = (unsigned short*)(w + 476053504ll);
  float* Wzt = (float*)(w + 478150656ll);
  float* Wrt = (float*)(w + 482344960ll);
  float* Wst = (float*)(w + 486539264ll);
  float* hbuf = (float*)(w + 490733568ll);
  float* zbuf = (float*)(w + 490995712ll);
  unsigned short* h_hi = (unsigned short*)(w + 491257856ll);
  unsigned short* h_lo = (unsigned short*)(w + 491388928ll);
  unsigned short* rh_hi = (unsigned short*)(w + 491520000ll);
  unsigned short* rh_lo = (unsigned short*)(w + 491651072ll);

  float* out = (float*)d_out;
  float* hfin = out + 33554432;  // 64*512*1024

  hipLaunchKernelGGL(pack_split_kernel, dim3(16384), dim3(256), 0, stream,
                     inputs, Xhi, Xlo, 16777216);
  hipLaunchKernelGGL(packT_split_kernel, dim3(2048), dim3(256), 0, stream,
                     Wz + 1048576, WzxThi, WzxTlo, 9, 1024);
  hipLaunchKernelGGL(packT_split_kernel, dim3(2048), dim3(256), 0, stream,
                     Wr + 1048576, WrxThi, WrxTlo, 9, 1024);
  hipLaunchKernelGGL(packT_split_kernel, dim3(2048), dim3(256), 0, stream,
                     Ws + 1048576, WsxThi, WsxTlo, 9, 1024);
  hipLaunchKernelGGL(packT_bf16_kernel, dim3(4096), dim3(256), 0, stream, Wo, WoT, 10, 1024);
  hipLaunchKernelGGL(transpose1024_kernel, dim3(4096), dim3(256), 0, stream, Wz, Wzt);
  hipLaunchKernelGGL(transpose1024_kernel, dim3(4096), dim3(256), 0, stream, Wr, Wrt);
  hipLaunchKernelGGL(transpose1024_kernel, dim3(4096), dim3(256), 0, stream, Ws, Wst);

  hipLaunchKernelGGL(gemm_bf16x2_kernel, dim3(16, 512), dim3(256), 0, stream,
                     Xhi, Xlo, WzxThi, WzxTlo, bz, xz, 32768, 1024, 512);
  hipLaunchKernelGGL(gemm_bf16x2_kernel, dim3(16, 512), dim3(256), 0, stream,
                     Xhi, Xlo, WrxThi, WrxTlo, br, xr, 32768, 1024, 512);
  hipLaunchKernelGGL(gemm_bf16x2_kernel, dim3(16, 512), dim3(256), 0, stream,
                     Xhi, Xlo, WsxThi, WsxTlo, bs, xs, 32768, 1024, 512);

  // MFMA recurrence: 128 blocks, 132096 B dynamic LDS (4 x [16][1032] shorts)
  void* args[] = {&xz, &xr, &xs, &Wzt, &Wrt, &Wst, &hbuf, &zbuf,
                  &h_hi, &h_lo, &rh_hi, &rh_lo, &hs_bf, &hfin};
  hipLaunchCooperativeKernel((const void*)recurrence_mfma_kernel, dim3(128), dim3(256),
                             args, 132096, stream);

  hipLaunchKernelGGL(gemm_bf16_kernel, dim3(16, 512), dim3(256), 0, stream,
                     hs_bf, WoT, bo, out, 32768, 1024, 1024, 1);
}